// Round 1
// baseline (42.907 us; speedup 1.0000x reference)
//
#include <hip/hip_runtime.h>

// Haar 2D: x (B=8, C=16, H=512, W=512) f32 -> out (B=8, 4*C=64, 256, 256) f32
// out channel layout: [LL(0..15) | LH(16..31) | HL(32..47) | HH(48..63)]
//
// Each thread: 2 adjacent output columns -> reads 2x float4 (2 rows x 4 cols
// of input), writes 4x float2 (one per subband plane). Fully coalesced.

#define B_ 8
#define C_ 16
#define H_ 512
#define W_ 512
#define HO_ 256
#define WO_ 256
#define WP_ 128                      // output-column pairs per row
#define PLANE_OUT (HO_ * WO_)        // 65536
#define SUB_STRIDE (C_ * PLANE_OUT)  // 16*65536 = 1048576 floats

__global__ __launch_bounds__(256) void haar2d_kernel(const float* __restrict__ x,
                                                     float* __restrict__ out) {
    const int idx = blockIdx.x * blockDim.x + threadIdx.x;
    // idx over (b, c, i, jp): jp in [0,128), i in [0,256), c in [0,16), b in [0,8)
    const int jp = idx & (WP_ - 1);
    const int i  = (idx >> 7) & (HO_ - 1);
    const int c  = (idx >> 15) & (C_ - 1);
    const int b  = idx >> 19;

    // input: rows 2i, 2i+1; cols 4*jp .. 4*jp+3
    const long in_base = ((long)(b * C_ + c) * H_ + 2 * i) * W_ + 4 * jp;
    const float4 r0 = *reinterpret_cast<const float4*>(x + in_base);
    const float4 r1 = *reinterpret_cast<const float4*>(x + in_base + W_);

    // block a: cols (2jp), block b: cols (2jp+1)
    const float ll_a = (r0.x + r0.y + r1.x + r1.y) * 0.5f;
    const float lh_a = (r0.x + r0.y - r1.x - r1.y) * 0.5f;
    const float hl_a = (r0.x - r0.y + r1.x - r1.y) * 0.5f;
    const float hh_a = (r0.x - r0.y - r1.x + r1.y) * 0.5f;

    const float ll_b = (r0.z + r0.w + r1.z + r1.w) * 0.5f;
    const float lh_b = (r0.z + r0.w - r1.z - r1.w) * 0.5f;
    const float hl_b = (r0.z - r0.w + r1.z - r1.w) * 0.5f;
    const float hh_b = (r0.z - r0.w - r1.z + r1.w) * 0.5f;

    // output: out[b][sub*16 + c][i][2jp .. 2jp+1]
    float* o = out + (long)b * (4 * SUB_STRIDE) + (long)c * PLANE_OUT
                   + (long)i * WO_ + 2 * jp;
    *reinterpret_cast<float2*>(o + 0L * SUB_STRIDE) = make_float2(ll_a, ll_b);
    *reinterpret_cast<float2*>(o + 1L * SUB_STRIDE) = make_float2(lh_a, lh_b);
    *reinterpret_cast<float2*>(o + 2L * SUB_STRIDE) = make_float2(hl_a, hl_b);
    *reinterpret_cast<float2*>(o + 3L * SUB_STRIDE) = make_float2(hh_a, hh_b);
}

extern "C" void kernel_launch(void* const* d_in, const int* in_sizes, int n_in,
                              void* d_out, int out_size, void* d_ws, size_t ws_size,
                              hipStream_t stream) {
    const float* x = (const float*)d_in[0];
    float* out = (float*)d_out;
    // total threads = 8*16*256*128 = 4,194,304
    const int threads = 256;
    const int blocks = (B_ * C_ * HO_ * WP_) / threads;  // 16384
    haar2d_kernel<<<blocks, threads, 0, stream>>>(x, out);
}